// Round 3
// baseline (272.129 us; speedup 1.0000x reference)
//
#include <hip/hip_runtime.h>

// Problem constants
#define L_SEQ   4096
#define BSZQ    8
#define ROWS    (BSZQ * L_SEQ)      // 32768
#define KC1     512                 // GEMM1 K  (= H)
#define NC1     1024                // GEMM1 out cols (= 2*N interleaved re/im)
#define KC2     1024                // GEMM2 K
#define NC2     512                 // GEMM2 out cols (= H)
#define CHUNK   64
#define NCHUNK  64                  // L_SEQ / CHUNK

typedef __attribute__((ext_vector_type(8))) short bfrag;   // 8 bf16 (4 VGPRs)
typedef __attribute__((ext_vector_type(4))) float ffrag;   // 4 fp32 acc

static __device__ __forceinline__ unsigned short f2bf(float f) {
    union { float f; unsigned int u; } v; v.f = f;
    unsigned int r = v.u + 0x7fffu + ((v.u >> 16) & 1u);   // round-nearest-even
    return (unsigned short)(r >> 16);
}
static __device__ __forceinline__ unsigned int pk2(float a, float b) {
    return (unsigned int)f2bf(a) | ((unsigned int)f2bf(b) << 16);
}
static __device__ __forceinline__ float2 unpk2(unsigned int u) {
    union { unsigned int u; float f; } a, b;
    a.u = u << 16;
    b.u = u & 0xffff0000u;
    return make_float2(a.f, b.f);
}

// async global->LDS, 16B per lane; lds dest = wave-uniform base + lane*16
static __device__ __forceinline__ void async16(const void* g, void* l) {
    __builtin_amdgcn_global_load_lds(
        (const __attribute__((address_space(1))) unsigned int*)g,
        (__attribute__((address_space(3))) unsigned int*)l,
        16, 0, 0);
}

// ---- fused prep: lam + Bt + Dt --------------------------------------------
// blocks 0..2047: Bt[n2][h] = bf16(B[h][n2])          (1024 x 512)
// blocks 2048..4095: Dt[j][2n+c] = bf16(+/- C[c][n][j]) (512 x 1024)
// block 4096: lam[n] = exp(-exp(nu_log)+i*exp(theta_log))
__global__ __launch_bounds__(256) void prep_all_kernel(
    const float* __restrict__ B, const float* __restrict__ C,
    const float* __restrict__ nu_log, const float* __restrict__ theta_log,
    unsigned short* __restrict__ Bt, unsigned short* __restrict__ Dt,
    float2* __restrict__ lam)
{
    int g = blockIdx.x, tid = threadIdx.x;
    if (g < 2048) {
        int idx = g * 256 + tid;                // 524288 total
        int n2 = idx >> 9, h = idx & 511;
        Bt[idx] = f2bf(B[(size_t)h * 1024 + n2]);
    } else if (g < 4096) {
        int idx = (g - 2048) * 256 + tid;       // 524288 total
        int j = idx >> 10, k = idx & 1023;
        int n = k >> 1, c = k & 1;
        float v = C[((size_t)c * 512 + n) * 512 + j];
        Dt[idx] = f2bf(c ? -v : v);
    } else {
#pragma unroll
        for (int r = 0; r < 2; r++) {
            int n = tid + r * 256;
            float mag = expf(-expf(nu_log[n]));
            float th  = expf(theta_log[n]);
            lam[n] = make_float2(mag * cosf(th), mag * sinf(th));
        }
    }
}

// ------------- u (fp32) -> ub (bf16) with length mask folded in -------------
__global__ __launch_bounds__(256) void conv_mask_kernel(
    const float* __restrict__ u, const int* __restrict__ lengths,
    unsigned short* __restrict__ ub)
{
    int idx = blockIdx.x * 256 + threadIdx.x;   // 2,097,152 total (x8 elems)
    int row = idx >> 6;                         // flat row (b*L + l)
    int l = row & (L_SEQ - 1), b = row >> 12;
    bool keep = (l < lengths[b]);
    union { unsigned int s[4]; float4 f; } o;
    if (keep) {
        const float4 a = *(const float4*)(u + (size_t)idx * 8);
        const float4 c = *(const float4*)(u + (size_t)idx * 8 + 4);
        o.s[0] = pk2(a.x, a.y); o.s[1] = pk2(a.z, a.w);
        o.s[2] = pk2(c.x, c.y); o.s[3] = pk2(c.z, c.w);
    } else {
        o.s[0] = o.s[1] = o.s[2] = o.s[3] = 0u;
    }
    *(float4*)(ub + (size_t)idx * 8) = o.f;
}

// ============ 128x128 BK=32 double-buffered issue-early GEMM ================
// Co[r,j] = sum_k A[r,k] * Bt[j,k].  4 waves (2x2), per-wave 64x64 output.
// LDS: 2 x (A 8KB + B 8KB) = 32 KB -> 4 blocks/CU co-resident; inter-block
// TLP covers staging stalls (the round-0 strength), while issue-early dbuf
// gives each iteration's loads the whole compute phase to fly before the
// __syncthreads drain (the round-0 weakness fixed).
// Swizzle (both sides): row has 4 16B chunks (64 B); stored chunk c holds
// global chunk c ^ ((r>>1)&3). Read of global chunk q at row r uses LDS
// chunk q ^ ((r>>1)&3): 16 lanes (stride 16 rows... m16 varies) spread over
// 8 bank-groups -> 2-way (free). Swizzle on the global SOURCE address is a
// permutation within each 64B line -> coalescing unchanged.
template<int KD, int ND, bool BF16OUT>
__global__ __launch_bounds__(256, 4) void gemm_db(
    const unsigned short* __restrict__ A,   // row-major [., KD] bf16
    const unsigned short* __restrict__ Bt,  // row-major [ND, KD] bf16
    void* __restrict__ Co)
{
    __shared__ __align__(16) unsigned short As[2][128 * 32];  // 2 x 8 KB
    __shared__ __align__(16) unsigned short Bs[2][128 * 32];  // 2 x 8 KB

    const int tid  = threadIdx.x;
    const int lane = tid & 63, w = tid >> 6;
    const int q = lane >> 4, m16 = lane & 15;
    const int wr = (w >> 1) * 64, wc = (w & 1) * 64;
    const int row0 = blockIdx.x * 128;
    const int col0 = blockIdx.y * 128;

    ffrag acc[4][4];
#pragma unroll
    for (int i = 0; i < 4; i++)
#pragma unroll
        for (int j = 0; j < 4; j++) acc[i][j] = (ffrag)0.f;

    // Stage one 128x32 bf16 tile (8 KB = 512 x 16B slots) at K-offset KT.
    // slot s = j*256+tid: r = s>>2, chunk = s&3; source chunk pre-swizzled.
#define STAGE_T(GP, TB, KT, GR0) do {                                          \
    _Pragma("unroll")                                                          \
    for (int j_ = 0; j_ < 2; j_++) {                                           \
        int s_ = j_ * 256 + tid;                                               \
        int r_ = s_ >> 2;                                                      \
        int cs_ = (s_ & 3) ^ ((r_ >> 1) & 3);                                  \
        async16(GP + (size_t)((GR0) + r_) * KD + (KT) + cs_ * 8,               \
                &TB[(size_t)(j_ * 256 + w * 64) * 8]);                         \
    }                                                                          \
} while (0)

    // prologue
    STAGE_T(A,  As[0], 0, row0);
    STAGE_T(Bt, Bs[0], 0, col0);
    __syncthreads();

    int c = 0;
    for (int kt = 0; kt < KD; kt += 32) {
        if (kt + 32 < KD) {                      // issue-early next tile
            STAGE_T(A,  As[c ^ 1], kt + 32, row0);
            STAGE_T(Bt, Bs[c ^ 1], kt + 32, col0);
        }
        bfrag a[4], b[4];
#pragma unroll
        for (int ri = 0; ri < 4; ri++) {
            int r_ = wr + ri * 16 + m16;
            a[ri] = *(const bfrag*)&As[c][r_ * 32 + (q ^ ((r_ >> 1) & 3)) * 8];
        }
#pragma unroll
        for (int ci = 0; ci < 4; ci++) {
            int r_ = wc + ci * 16 + m16;
            b[ci] = *(const bfrag*)&Bs[c][r_ * 32 + (q ^ ((r_ >> 1) & 3)) * 8];
        }
#pragma unroll
        for (int ri = 0; ri < 4; ri++)
#pragma unroll
            for (int ci = 0; ci < 4; ci++)
                acc[ri][ci] = __builtin_amdgcn_mfma_f32_16x16x32_bf16(
                    a[ri], b[ci], acc[ri][ci], 0, 0, 0);
        __syncthreads();        // drains staged loads; loads flew over compute
        c ^= 1;
    }
#undef STAGE_T

    if (BF16OUT) {
        // In-register re/im pairing (verified in round 2, 8-wave form):
        // within frag ci, lanes 2j/2j+1 hold real cols; shfl_xor(1) exchanges
        // the pair; even lane packs re, odd packs im. One dword per lane.
        unsigned int* Cb = (unsigned int*)Co;
        const int colc0 = (col0 >> 1) + (w & 1) * 32;
#pragma unroll
        for (int ri = 0; ri < 4; ri++)
#pragma unroll
            for (int cp = 0; cp < 2; cp++)
#pragma unroll
                for (int r4 = 0; r4 < 4; r4++) {
                    float a0 = acc[ri][cp * 2][r4];
                    float a1 = acc[ri][cp * 2 + 1][r4];
                    float b0 = __shfl_xor(a0, 1);
                    float b1 = __shfl_xor(a1, 1);
                    unsigned int uo = (m16 & 1) ? pk2(b1, a1) : pk2(a0, b0);
                    int row = row0 + wr + ri * 16 + q * 4 + r4;
                    int ccol = (cp * 2 + (m16 & 1)) * 8 + (m16 >> 1);
                    Cb[(size_t)row * (ND / 2) + colc0 + ccol] = uo;
                }
    } else {
        // fp32 dword scatter: per (ri,r4,ci) 16 lanes = one full 64B line.
        float* Cf = (float*)Co;
#pragma unroll
        for (int ri = 0; ri < 4; ri++)
#pragma unroll
            for (int r4 = 0; r4 < 4; r4++) {
                int row = row0 + wr + ri * 16 + q * 4 + r4;
#pragma unroll
                for (int ci = 0; ci < 4; ci++) {
                    int col = col0 + wc + ci * 16 + m16;
                    Cf[(size_t)row * ND + col] = acc[ri][ci][r4];
                }
            }
    }
}

// ------- scan phase 1: chunk-final states only (bu is packed bf16) ----------
__global__ __launch_bounds__(512) void scan_states_kernel(
    const unsigned int* __restrict__ bu, const float2* __restrict__ lam,
    float2* __restrict__ states)
{
    int n = threadIdx.x;
    int b = blockIdx.x >> 6;
    int c = blockIdx.x & 63;
    float2 lm = lam[n];
    float xr = 0.f, xi = 0.f;
    bool fwd = (n < 256);
    int l0 = fwd ? (c * CHUNK) : (c * CHUNK + CHUNK - 1);
    const unsigned int* p = bu + ((size_t)b * L_SEQ + l0) * 512 + n;
    ptrdiff_t step = fwd ? 512 : -512;
#pragma unroll 8
    for (int t = 0; t < CHUNK; t++) {
        float2 v = unpk2(*p);
        float nr = lm.x * xr - lm.y * xi + v.x;
        float ni = lm.x * xi + lm.y * xr + v.y;
        xr = nr; xi = ni;
        p += step;
    }
    states[((size_t)b * NCHUNK + c) * 512 + n] = make_float2(xr, xi);
}

// ---------------- scan phase 2: combine chunk states -> exclusive carries ---
// Group-of-8 state preload: 8 independent loads in flight per group instead of
// 64 serial HBM round-trips (this kernel has only 8 blocks -> latency-bound).
__global__ __launch_bounds__(512) void scan_combine_kernel(
    const float2* __restrict__ states, float2* __restrict__ carries,
    const float2* __restrict__ lam)
{
    int n = threadIdx.x;
    int b = blockIdx.x;
    float2 lm = lam[n];
    float ar = lm.x, ai = lm.y;          // lam^64 by 6 squarings
#pragma unroll
    for (int i = 0; i < 6; i++) {
        float nr = ar * ar - ai * ai;
        ai = 2.f * ar * ai;
        ar = nr;
    }
    float cr = 0.f, ci = 0.f;
    bool fwd = (n < 256);
    for (int g = 0; g < 8; g++) {
        float2 s[8];
#pragma unroll
        for (int k = 0; k < 8; k++) {
            int c = fwd ? (g * 8 + k) : (63 - (g * 8 + k));
            s[k] = states[((size_t)b * NCHUNK + c) * 512 + n];
        }
#pragma unroll
        for (int k = 0; k < 8; k++) {
            int c = fwd ? (g * 8 + k) : (63 - (g * 8 + k));
            carries[((size_t)b * NCHUNK + c) * 512 + n] = make_float2(cr, ci);
            float nr = ar * cr - ai * ci + s[k].x;
            float ni = ar * ci + ai * cr + s[k].y;
            cr = nr; ci = ni;
        }
    }
}

// -------- scan phase 3: re-scan seeded with carry + mask, in place ----------
__global__ __launch_bounds__(512) void scan_apply_kernel(
    unsigned int* __restrict__ bu, const float2* __restrict__ carries,
    const float2* __restrict__ lam, const int* __restrict__ lengths)
{
    int n = threadIdx.x;
    int b = blockIdx.x >> 6;
    int c = blockIdx.x & 63;
    int len = lengths[b];
    float2 lm = lam[n];
    float2 cy = carries[((size_t)b * NCHUNK + c) * 512 + n];
    bool fwd = (n < 256);
    int l0 = fwd ? (c * CHUNK) : (c * CHUNK + CHUNK - 1);
    int dl = fwd ? 1 : -1;
    unsigned int* p = bu + ((size_t)b * L_SEQ + l0) * 512 + n;
    ptrdiff_t step = fwd ? 512 : -512;
    float xr = cy.x, xi = cy.y;
    int l = l0;
#pragma unroll 8
    for (int t = 0; t < CHUNK; t++) {
        float2 v = unpk2(*p);
        float nr = lm.x * xr - lm.y * xi + v.x;
        float ni = lm.x * xi + lm.y * xr + v.y;
        xr = nr; xi = ni;
        *p = (l >= len) ? 0u : pk2(xr, xi);
        p += step; l += dl;
    }
}

// ---------------- launch ----------------------------------------------------
extern "C" void kernel_launch(void* const* d_in, const int* in_sizes, int n_in,
                              void* d_out, int out_size, void* d_ws, size_t ws_size,
                              hipStream_t stream)
{
    const float* u        = (const float*)d_in[0];   // (8,4096,512)
    const int*   lengths  = (const int*)  d_in[1];   // (8,)
    const float* nu_log   = (const float*)d_in[2];   // (512,)
    const float* theta_log= (const float*)d_in[3];   // (512,)
    const float* B        = (const float*)d_in[4];   // (512,512,2) == (512 x 1024)
    const float* C        = (const float*)d_in[5];   // (2,512,512)
    float* y = (float*)d_out;                        // (8,4096,512)

    char* wp = (char*)d_ws;
    float2* lam     = (float2*)wp;  wp += 4096;
    float2* states  = (float2*)wp;  wp += (size_t)BSZQ * NCHUNK * 512 * 8;  // 2 MB
    float2* carries = (float2*)wp;  wp += (size_t)BSZQ * NCHUNK * 512 * 8;  // 2 MB
    unsigned int* bu = (unsigned int*)wp; wp += (size_t)ROWS * 512 * 4;     // 64 MB packed bf16
    unsigned short* ub = (unsigned short*)wp; wp += (size_t)ROWS * 512 * 2; // 32 MB
    unsigned short* Bt = (unsigned short*)wp; wp += (size_t)NC1 * KC1 * 2;  // 1 MB
    unsigned short* Dt = (unsigned short*)wp; wp += (size_t)NC2 * KC2 * 2;  // 1 MB

    prep_all_kernel<<<4097, 256, 0, stream>>>(B, C, nu_log, theta_log, Bt, Dt, lam);
    conv_mask_kernel<<<8192, 256, 0, stream>>>(u, lengths, ub);

    // GEMM1: bu(packed bf16) = ub @ Bt^T  (mask folded into ub)
    {
        dim3 grid(ROWS / 128, NC1 / 128);   // (256, 8)
        gemm_db<KC1, NC1, true><<<grid, 256, 0, stream>>>(ub, Bt, bu);
    }

    scan_states_kernel<<<BSZQ * NCHUNK, 512, 0, stream>>>(bu, lam, states);
    scan_combine_kernel<<<BSZQ, 512, 0, stream>>>(states, carries, lam);
    scan_apply_kernel<<<BSZQ * NCHUNK, 512, 0, stream>>>(bu, carries, lam, lengths);

    // GEMM2: y = bu(=x, packed bf16) @ Dt^T, fp32 out
    {
        dim3 grid(ROWS / 128, NC2 / 128);   // (256, 4)
        gemm_db<KC2, NC2, false><<<grid, 256, 0, stream>>>(
            (const unsigned short*)bu, Dt, y);
    }
}